// Round 1
// baseline (669.649 us; speedup 1.0000x reference)
//
#include <hip/hip_runtime.h>

#define NPTS 524288
#define NSEG 64
// C = 512 (K), H = 256 (N of the GEMM)

typedef __bf16 bf16x8 __attribute__((ext_vector_type(8)));
typedef float f32x4 __attribute__((ext_vector_type(4)));

__device__ __forceinline__ unsigned int f2bf(float f) {
  unsigned int u = __float_as_uint(f);
  return (u + 0x7FFFu + ((u >> 16) & 1u)) >> 16;  // RNE bf16
}

// ---------------- prep: w1 [512][256] f32 -> bf16 packed [(k>>3)][n][k&7] ----------------
// B-fragment for mfma_f32_16x16x32_bf16: lane holds B[k = 8*(lane>>4)+i][n = lane&15],
// i=0..7 -> one contiguous 16B load per lane in this layout, coalesced across lanes.
__global__ void prep_w1(const float* __restrict__ w1, unsigned short* __restrict__ w1p) {
  int idx = blockIdx.x * 256 + threadIdx.x;   // 0..131071
  int k = idx >> 8, n = idx & 255;
  w1p[((k >> 3) << 11) + (n << 3) + (k & 7)] = (unsigned short)f2bf(w1[idx]);
}

__global__ void zero_out(float* __restrict__ out) {
  out[blockIdx.x * 256 + threadIdx.x] = 0.0f;  // grid covers exactly 64*512
}

// ---------------- kernel A: fused LN -> bf16 MFMA GEMM -> GELU -> dot(w2) -> s[i] ----------------
// Block: 64 rows, 256 threads (4 waves). Wave w owns n-cols [w*64, w*64+64).
__global__ __launch_bounds__(256, 2) void score_kernel(
    const float* __restrict__ feats, const float* __restrict__ ln_w,
    const float* __restrict__ ln_b, const unsigned short* __restrict__ w1p,
    const float* __restrict__ b1, const float* __restrict__ w2,
    const float* __restrict__ b2, float* __restrict__ s_out) {
  __shared__ __align__(16) unsigned short xs[64 * 512];  // 64KB bf16 x-tile, XOR-swizzled
  __shared__ float sred[4][64];
  char* xsb = (char*)xs;
  const int tid = threadIdx.x;
  const int lane = tid & 63;
  const int wid = tid >> 6;
  const long row0 = (long)blockIdx.x * 64;

  // ---- Phase 1: LayerNorm, one wave per row (16 rows/wave), write bf16 x to LDS ----
  const int c0 = lane * 4;  // this lane owns cols c0..c0+3 and 256+c0..256+c0+3
  const float4 lw0 = *(const float4*)(ln_w + c0);
  const float4 lw1 = *(const float4*)(ln_w + 256 + c0);
  const float4 lb0 = *(const float4*)(ln_b + c0);
  const float4 lb1 = *(const float4*)(ln_b + 256 + c0);

  #pragma unroll 2
  for (int rr = 0; rr < 16; ++rr) {
    const int row = wid * 16 + rr;
    const float* rp = feats + (row0 + row) * 512;
    const float4 v0 = *(const float4*)(rp + c0);
    const float4 v1 = *(const float4*)(rp + 256 + c0);
    float sum = (v0.x + v0.y) + (v0.z + v0.w) + (v1.x + v1.y) + (v1.z + v1.w);
    float sq  = v0.x * v0.x + v0.y * v0.y + v0.z * v0.z + v0.w * v0.w
              + v1.x * v1.x + v1.y * v1.y + v1.z * v1.z + v1.w * v1.w;
    #pragma unroll
    for (int off = 32; off >= 1; off >>= 1) {
      sum += __shfl_xor(sum, off);
      sq  += __shfl_xor(sq, off);
    }
    const float mean = sum * (1.0f / 512.0f);
    const float var  = sq * (1.0f / 512.0f) - mean * mean;  // ddof=0, matches jnp.var
    const float rstd = rsqrtf(var + 1e-5f);
    const float x0 = (v0.x - mean) * rstd * lw0.x + lb0.x;
    const float x1 = (v0.y - mean) * rstd * lw0.y + lb0.y;
    const float x2 = (v0.z - mean) * rstd * lw0.z + lb0.z;
    const float x3 = (v0.w - mean) * rstd * lw0.w + lb0.w;
    const float y0 = (v1.x - mean) * rstd * lw1.x + lb1.x;
    const float y1 = (v1.y - mean) * rstd * lw1.y + lb1.y;
    const float y2 = (v1.z - mean) * rstd * lw1.z + lb1.z;
    const float y3 = (v1.w - mean) * rstd * lw1.w + lb1.w;
    const unsigned int p0 = f2bf(x0) | (f2bf(x1) << 16);
    const unsigned int p1 = f2bf(x2) | (f2bf(x3) << 16);
    const unsigned int p2 = f2bf(y0) | (f2bf(y1) << 16);
    const unsigned int p3 = f2bf(y2) | (f2bf(y3) << 16);
    // swizzle: flip byte bits 4-6 with row&7 -> conflict-free ds_read_b128 later
    const unsigned int a0 = ((unsigned int)(row * 1024 + c0 * 2)) ^ (((unsigned int)(row & 7)) << 4);
    const unsigned int a1 = ((unsigned int)(row * 1024 + 512 + c0 * 2)) ^ (((unsigned int)(row & 7)) << 4);
    *(uint2*)(xsb + a0) = make_uint2(p0, p1);
    *(uint2*)(xsb + a1) = make_uint2(p2, p3);
  }
  __syncthreads();

  // ---- Phase 2: GEMM  h[64x256] = x[64x512] @ w1, K-loop of 16 steps of 32 ----
  const int l15 = lane & 15, l4 = lane >> 4;
  const int nb = wid * 64;
  f32x4 acc[4][4];
  #pragma unroll
  for (int i = 0; i < 4; ++i)
    #pragma unroll
    for (int j = 0; j < 4; ++j)
      acc[i][j] = f32x4{0.f, 0.f, 0.f, 0.f};

  #pragma unroll 4
  for (int ks = 0; ks < 16; ++ks) {
    bf16x8 av[4], bv[4];
    #pragma unroll
    for (int mt = 0; mt < 4; ++mt) {
      // A-frag: A[m = mt*16 + (lane&15)][k = ks*32 + 8*(lane>>4) + i]
      const int row = mt * 16 + l15;
      const unsigned int ad =
          ((unsigned int)(row * 1024 + ks * 64 + l4 * 16)) ^ (((unsigned int)(row & 7)) << 4);
      av[mt] = *(const bf16x8*)(xsb + ad);
    }
    #pragma unroll
    for (int nt = 0; nt < 4; ++nt) {
      // B-frag from packed w1: element group [(ks*4 + l4)][n][0..7]
      const int idx = (((ks * 4 + l4) << 8) + nb + nt * 16 + l15) << 3;
      bv[nt] = *(const bf16x8*)(w1p + idx);
    }
    #pragma unroll
    for (int mt = 0; mt < 4; ++mt)
      #pragma unroll
      for (int nt = 0; nt < 4; ++nt)
        acc[mt][nt] = __builtin_amdgcn_mfma_f32_16x16x32_bf16(av[mt], bv[nt], acc[mt][nt], 0, 0, 0);
  }

  // ---- Epilogue: h = gelu(acc + b1); s_row = sum_n h*w2 + b2 ----
  float b1v[4], w2v[4];
  #pragma unroll
  for (int nt = 0; nt < 4; ++nt) {
    const int n = nb + nt * 16 + l15;
    b1v[nt] = b1[n];
    w2v[nt] = w2[n];
  }
  #pragma unroll
  for (int mt = 0; mt < 4; ++mt) {
    #pragma unroll
    for (int r = 0; r < 4; ++r) {
      // C/D layout: col = lane&15, row = (lane>>4)*4 + r  (within 16x16 tile)
      float v = 0.0f;
      #pragma unroll
      for (int nt = 0; nt < 4; ++nt) {
        const float h = acc[mt][nt][r] + b1v[nt];
        const float g = 0.5f * h * (1.0f + erff(h * 0.70710678118654752f));  // exact GELU
        v += g * w2v[nt];
      }
      v += __shfl_xor(v, 1);
      v += __shfl_xor(v, 2);
      v += __shfl_xor(v, 4);
      v += __shfl_xor(v, 8);
      if (l15 == 0) sred[wid][mt * 16 + l4 * 4 + r] = v;
    }
  }
  __syncthreads();
  if (tid < 64) {
    s_out[row0 + tid] = sred[0][tid] + sred[1][tid] + sred[2][tid] + sred[3][tid] + b2[0];
  }
}

// ---------------- kernel B: per-segment max and 1/sum(exp) ----------------
__global__ void seg_stats(const float* __restrict__ s, const int* __restrict__ offs,
                          float* __restrict__ mz) {
  const int b = blockIdx.x;
  const int start = offs[b], end = offs[b + 1];
  const int tid = threadIdx.x;
  const int lane = tid & 63, wid = tid >> 6;
  __shared__ float red[4];

  float lm = -INFINITY;
  for (int i = start + tid; i < end; i += 256) lm = fmaxf(lm, s[i]);
  #pragma unroll
  for (int off = 32; off >= 1; off >>= 1) lm = fmaxf(lm, __shfl_xor(lm, off));
  if (lane == 0) red[wid] = lm;
  __syncthreads();
  const float m = fmaxf(fmaxf(red[0], red[1]), fmaxf(red[2], red[3]));
  __syncthreads();

  float ls = 0.0f;
  for (int i = start + tid; i < end; i += 256) ls += expf(s[i] - m);
  #pragma unroll
  for (int off = 32; off >= 1; off >>= 1) ls += __shfl_xor(ls, off);
  if (lane == 0) red[wid] = ls;
  __syncthreads();
  if (tid == 0) {
    const float z = red[0] + red[1] + red[2] + red[3];
    mz[b] = m;
    mz[NSEG + b] = 1.0f / z;
  }
}

// ---------------- kernel C: pooled[seg][c] += feats[i][c] * w_i ----------------
// Block = 256 contiguous rows; each thread owns 2 cols, register accumulator,
// flushed with atomics only on segment change / chunk end.
__global__ __launch_bounds__(256) void pool_kernel(
    const float* __restrict__ feats, const float* __restrict__ s,
    const float* __restrict__ mz, const int* __restrict__ offs,
    float* __restrict__ out) {
  __shared__ int soffs[NSEG + 1];
  __shared__ float sm[NSEG], sz[NSEG];
  const int tid = threadIdx.x;
  if (tid < NSEG + 1) soffs[tid] = offs[tid];
  if (tid < NSEG) { sm[tid] = mz[tid]; sz[tid] = mz[NSEG + tid]; }
  __syncthreads();

  const int r0 = blockIdx.x * 256;
  int seg = 0;
  while (soffs[seg + 1] <= r0) ++seg;
  float m = sm[seg], iz = sz[seg];

  const float2* f2p = (const float2*)feats;  // row stride = 256 float2
  float2 acc = make_float2(0.0f, 0.0f);
  float2 nxt = f2p[(size_t)r0 * 256 + tid];
  for (int r = r0; r < r0 + 256; ++r) {
    const float2 cur = nxt;
    if (r + 1 < NPTS) nxt = f2p[(size_t)(r + 1) * 256 + tid];
    if (r >= soffs[seg + 1]) {
      atomicAdd(&out[seg * 512 + tid * 2], acc.x);
      atomicAdd(&out[seg * 512 + tid * 2 + 1], acc.y);
      acc.x = 0.0f; acc.y = 0.0f;
      do { ++seg; } while (r >= soffs[seg + 1]);
      m = sm[seg]; iz = sz[seg];
    }
    const float wgt = expf(s[r] - m) * iz;
    acc.x += cur.x * wgt;
    acc.y += cur.y * wgt;
  }
  atomicAdd(&out[seg * 512 + tid * 2], acc.x);
  atomicAdd(&out[seg * 512 + tid * 2 + 1], acc.y);
}

extern "C" void kernel_launch(void* const* d_in, const int* in_sizes, int n_in,
                              void* d_out, int out_size, void* d_ws, size_t ws_size,
                              hipStream_t stream) {
  const float* feats = (const float*)d_in[0];
  const float* ln_w  = (const float*)d_in[1];
  const float* ln_b  = (const float*)d_in[2];
  const float* w1    = (const float*)d_in[3];
  const float* b1    = (const float*)d_in[4];
  const float* w2    = (const float*)d_in[5];
  const float* b2    = (const float*)d_in[6];
  const int* offs    = (const int*)d_in[7];
  float* out = (float*)d_out;

  char* ws = (char*)d_ws;
  float* s_buf = (float*)ws;                                   // N f32 = 2 MB
  float* mz    = (float*)(ws + (size_t)NPTS * 4);              // 128 f32
  unsigned short* w1p = (unsigned short*)(ws + (size_t)NPTS * 4 + 4096);  // 256 KB bf16

  prep_w1<<<512, 256, 0, stream>>>(w1, w1p);
  zero_out<<<(NSEG * 512) / 256, 256, 0, stream>>>(out);
  score_kernel<<<NPTS / 64, 256, 0, stream>>>(feats, ln_w, ln_b, w1p, b1, w2, b2, s_buf);
  seg_stats<<<NSEG, 256, 0, stream>>>(s_buf, offs, mz);
  pool_kernel<<<NPTS / 256, 256, 0, stream>>>(feats, s_buf, mz, offs, out);
}